// Round 2
// baseline (633.470 us; speedup 1.0000x reference)
//
#include <hip/hip_runtime.h>
#include <hip/hip_bf16.h>
#include <math.h>

#define D 256

typedef short s16x8 __attribute__((ext_vector_type(8)));
typedef float f32x4 __attribute__((ext_vector_type(4)));

__device__ __forceinline__ unsigned short f2bf(float f) {
    unsigned int u = __builtin_bit_cast(unsigned int, f);
    unsigned int r = (u + 0x7fffu + ((u >> 16) & 1u)) >> 16;  // RNE
    return (unsigned short)r;
}
__device__ __forceinline__ float bf2f(unsigned short s) {
    unsigned int u = ((unsigned int)s) << 16;
    return __builtin_bit_cast(float, u);
}

// Wsw[((kt*16 + nt)*64 + lane)*8 + j] = bf16(W[kt*32 + (lane>>4)*8 + j][nt*16 + (lane&15)])
__global__ void swizzle_w(const float* __restrict__ W1, const float* __restrict__ Wr,
                          unsigned short* __restrict__ W1sw, unsigned short* __restrict__ Wrsw) {
    int idx = blockIdx.x * blockDim.x + threadIdx.x;  // 0 .. 2*65536-1
    int m = idx >> 16;
    int t = idx & 65535;
    const float* src = m ? Wr : W1;
    unsigned short* dst = m ? Wrsw : W1sw;
    int j = t & 7, lane = (t >> 3) & 63, nt = (t >> 9) & 15, kt = t >> 13;
    int k = kt * 32 + (lane >> 4) * 8 + j;
    int n = nt * 16 + (lane & 15);
    dst[t] = f2bf(src[k * D + n]);
}

__global__ void build_row_ptr(const int* __restrict__ rows, int* __restrict__ rp, int N, int E) {
    int r = blockIdx.x * blockDim.x + threadIdx.x;
    if (r > N) return;
    int lo = 0, hi = E;
    while (lo < hi) {
        int mid = (lo + hi) >> 1;
        if (rows[mid] < r) lo = mid + 1; else hi = mid;
    }
    rp[r] = lo;
}

// ---------------- GEMM: B persistent in registers, A staged in LDS ----------------
// Block = 512 thr = 8 waves. Wave w owns cols [w*32, w*32+32).
// h/agg layout: GROUP-MAJOR [16][N][16] bf16 — group g = col>>4 owns a contiguous
// 3.2 MB slice so the scatter's per-XCD gather working set fits one 4 MB L2.

__device__ __forceinline__ void stage_a_frag(const float* __restrict__ Xrow, int k0,
                                             unsigned short* __restrict__ lA, int fgi) {
    float4 f0 = *(const float4*)(Xrow + k0);
    float4 f1 = *(const float4*)(Xrow + k0 + 4);
    s16x8 sf;
    sf[0] = (short)f2bf(f0.x); sf[1] = (short)f2bf(f0.y);
    sf[2] = (short)f2bf(f0.z); sf[3] = (short)f2bf(f0.w);
    sf[4] = (short)f2bf(f1.x); sf[5] = (short)f2bf(f1.y);
    sf[6] = (short)f2bf(f1.z); sf[7] = (short)f2bf(f1.w);
    *(s16x8*)(lA + (size_t)fgi * 8) = sf;
}

__global__ __launch_bounds__(512) void gemm1_b(const float* __restrict__ X,
                                               const unsigned short* __restrict__ Wsw,
                                               unsigned short* __restrict__ h,
                                               int N, int numTiles) {
    __shared__ unsigned short lA[2 * 8 * 64 * 8];  // 16 KB
    int t = threadIdx.x;
    int lane = t & 63;
    int wave = t >> 6;
    int quad = lane >> 4;

    s16x8 bfr[2][8];
#pragma unroll
    for (int ntl = 0; ntl < 2; ntl++) {
        int nt = wave * 2 + ntl;
#pragma unroll
        for (int kt = 0; kt < 8; kt++)
            bfr[ntl][kt] = *(const s16x8*)(Wsw + ((size_t)((kt * 16 + nt) * 64 + lane)) * 8);
    }

    for (int tile = blockIdx.x; tile < numTiles; tile += gridDim.x) {
#pragma unroll
        for (int q = 0; q < 2; q++) {
            int fgi = q * 512 + t;
            int mt = fgi >> 9, kt = (fgi >> 6) & 7, ll = fgi & 63;
            int rl = ll & 15, qd = ll >> 4;
            int grow = tile * 32 + mt * 16 + rl;
            if (grow >= N) grow = N - 1;
            stage_a_frag(X + (size_t)grow * D, kt * 32 + qd * 8, lA, fgi);
        }
        __syncthreads();

        f32x4 acc[2][2];
#pragma unroll
        for (int mt = 0; mt < 2; mt++)
#pragma unroll
            for (int ntl = 0; ntl < 2; ntl++) acc[mt][ntl] = (f32x4){0.f, 0.f, 0.f, 0.f};

#pragma unroll
        for (int mt = 0; mt < 2; mt++)
#pragma unroll
            for (int kt = 0; kt < 8; kt++) {
                s16x8 a = *(const s16x8*)(lA + (size_t)(((mt * 8 + kt) * 64 + lane)) * 8);
                acc[mt][0] = __builtin_amdgcn_mfma_f32_16x16x32_bf16(a, bfr[0][kt], acc[mt][0], 0, 0, 0);
                acc[mt][1] = __builtin_amdgcn_mfma_f32_16x16x32_bf16(a, bfr[1][kt], acc[mt][1], 0, 0, 0);
            }

#pragma unroll
        for (int mt = 0; mt < 2; mt++)
#pragma unroll
            for (int ntl = 0; ntl < 2; ntl++) {
                int g = wave * 2 + ntl;           // column group
                int c = lane & 15;                // col within group
#pragma unroll
                for (int r = 0; r < 4; r++) {
                    int grow = tile * 32 + mt * 16 + quad * 4 + r;
                    if (grow < N)
                        h[(size_t)g * N * 16 + (size_t)grow * 16 + c] = f2bf(acc[mt][ntl][r]);
                }
            }
        __syncthreads();
    }
}

__global__ __launch_bounds__(512) void gemm2_b(const float* __restrict__ X,
                                               const int* __restrict__ perm,
                                               const unsigned short* __restrict__ Wsw,
                                               const float* __restrict__ br,
                                               const unsigned short* __restrict__ agg,
                                               float* __restrict__ out,
                                               int N, int numTiles) {
    __shared__ unsigned short lA[2 * 8 * 64 * 8];  // 16 KB
    int t = threadIdx.x;
    int lane = t & 63;
    int wave = t >> 6;
    int quad = lane >> 4;

    s16x8 bfr[2][8];
#pragma unroll
    for (int ntl = 0; ntl < 2; ntl++) {
        int nt = wave * 2 + ntl;
#pragma unroll
        for (int kt = 0; kt < 8; kt++)
            bfr[ntl][kt] = *(const s16x8*)(Wsw + ((size_t)((kt * 16 + nt) * 64 + lane)) * 8);
    }

    for (int tile = blockIdx.x; tile < numTiles; tile += gridDim.x) {
#pragma unroll
        for (int q = 0; q < 2; q++) {
            int fgi = q * 512 + t;
            int mt = fgi >> 9, kt = (fgi >> 6) & 7, ll = fgi & 63;
            int rl = ll & 15, qd = ll >> 4;
            int grow = tile * 32 + mt * 16 + rl;
            if (grow >= N) grow = N - 1;
            int pr = perm[grow];
            stage_a_frag(X + (size_t)pr * D, kt * 32 + qd * 8, lA, fgi);
        }
        __syncthreads();

        f32x4 acc[2][2];
#pragma unroll
        for (int mt = 0; mt < 2; mt++)
#pragma unroll
            for (int ntl = 0; ntl < 2; ntl++) acc[mt][ntl] = (f32x4){0.f, 0.f, 0.f, 0.f};

#pragma unroll
        for (int mt = 0; mt < 2; mt++)
#pragma unroll
            for (int kt = 0; kt < 8; kt++) {
                s16x8 a = *(const s16x8*)(lA + (size_t)(((mt * 8 + kt) * 64 + lane)) * 8);
                acc[mt][0] = __builtin_amdgcn_mfma_f32_16x16x32_bf16(a, bfr[0][kt], acc[mt][0], 0, 0, 0);
                acc[mt][1] = __builtin_amdgcn_mfma_f32_16x16x32_bf16(a, bfr[1][kt], acc[mt][1], 0, 0, 0);
            }

        // epilogue: left = lA (bf16 of X[perm[row]]) -> no global gather
#pragma unroll
        for (int mt = 0; mt < 2; mt++) {
#pragma unroll
            for (int ntl = 0; ntl < 2; ntl++) {
                int g = wave * 2 + ntl;
                int cc = lane & 15;
                int col = g * 16 + cc;
                float b = br[col];
                int kt2 = col >> 5, qd2 = (col >> 3) & 3, j2 = col & 7;
#pragma unroll
                for (int r = 0; r < 4; r++) {
                    int rt = mt * 16 + quad * 4 + r;
                    int grow = tile * 32 + rt;
                    if (grow < N) {
                        float pre = acc[mt][ntl][r] + b;
                        float gate = 1.f / (1.f + __expf(-pre));
                        float gcn = bf2f(agg[(size_t)g * N * 16 + (size_t)grow * 16 + cc]);
                        float left = bf2f(lA[(size_t)(((mt * 8 + kt2) * 64 + qd2 * 16 + (rt & 15))) * 8 + j2]);
                        out[(size_t)grow * D + col] = gate * gcn + (1.f - gate) * left;
                    }
                }
            }
        }
        __syncthreads();
    }
}

// ---------------- Scatter: column-group partitioned, XCD-pinned, L2-resident ----------
// 16 groups x 16 cols. Group slice = N*32B = 3.2 MB contiguous (fits 4 MB per-XCD L2).
// bid%8 = XCD (empirical round-robin): XCD x runs group 2x fully, then 2x+1.
// Wave = 1 row: 8 subwaves of 8 lanes, each subwave one edge, lane covers 2 cols.
__global__ __launch_bounds__(256) void scatter3(const unsigned int* __restrict__ hg,
                                                const int* __restrict__ rp,
                                                const int* __restrict__ cols,
                                                const float* __restrict__ vals,
                                                unsigned int* __restrict__ aggg,
                                                int N, int E, int BPG) {
    int bid = blockIdx.x;
    int x = bid & 7;
    int j = bid >> 3;
    int hi = (j >= BPG) ? 1 : 0;
    int g = 2 * x + hi;
    int bg = j - hi * BPG;
    int wave = threadIdx.x >> 6;
    int lane = threadIdx.x & 63;
    int s = lane >> 3;     // subwave = edge slot
    int ci = lane & 7;     // uint (2 cols) within 32B row-chunk
    const unsigned int* hbase = hg + (size_t)g * N * 8;
    unsigned int* abase = aggg + (size_t)g * N * 8;
    int stride = BPG * 4;
    for (int row = bg * 4 + wave; row < N; row += stride) {
        int start = rp[row], end = rp[row + 1];
        float a0 = 0.f, a1 = 0.f;
        for (int base = start; base < end; base += 64) {
            int ii = base + lane;
            int iic = ii < E ? ii : E - 1;
            int cl = cols[iic];
            int vb = __builtin_bit_cast(int, vals[iic]);
            int n = end - base; if (n > 64) n = 64;
            for (int i = 0; i < n; i += 8) {
                int idx = (i + s) << 2;
                int c = __builtin_amdgcn_ds_bpermute(idx, cl);
                int vvb = __builtin_amdgcn_ds_bpermute(idx, vb);
                float v = (i + s) < n ? __builtin_bit_cast(float, vvb) : 0.f;
                unsigned int u = hbase[(size_t)c * 8 + ci];
                float x0 = __builtin_bit_cast(float, u << 16);
                float x1 = __builtin_bit_cast(float, u & 0xffff0000u);
                a0 += v * x0;
                a1 += v * x1;
            }
        }
        a0 += __shfl_xor(a0, 8, 64);  a1 += __shfl_xor(a1, 8, 64);
        a0 += __shfl_xor(a0, 16, 64); a1 += __shfl_xor(a1, 16, 64);
        a0 += __shfl_xor(a0, 32, 64); a1 += __shfl_xor(a1, 32, 64);
        if (s == 0) {
            a0 = fmaxf(a0, 0.f); a1 = fmaxf(a1, 0.f);
            unsigned int o = (unsigned int)f2bf(a0) | ((unsigned int)f2bf(a1) << 16);
            abase[(size_t)row * 8 + ci] = o;
        }
    }
}

extern "C" void kernel_launch(void* const* d_in, const int* in_sizes, int n_in,
                              void* d_out, int out_size, void* d_ws, size_t ws_size,
                              hipStream_t stream) {
    const float* right = (const float*)d_in[0];
    const float* W1    = (const float*)d_in[1];
    const float* Wr    = (const float*)d_in[2];
    const float* br    = (const float*)d_in[3];
    const float* evals = (const float*)d_in[4];
    const int*   erows = (const int*)d_in[5];
    const int*   ecols = (const int*)d_in[6];
    const int*   perm  = (const int*)d_in[7];
    int N = in_sizes[7];
    int E = in_sizes[4];
    float* out = (float*)d_out;

    char* ws = (char*)d_ws;
    unsigned short* W1sw = (unsigned short*)ws;
    unsigned short* Wrsw = W1sw + D * D;
    int* rp = (int*)(ws + (size_t)2 * D * D * 2);
    size_t off = (size_t)2 * D * D * 2 + 4 * (size_t)(N + 1);
    off = (off + 255) & ~(size_t)255;
    unsigned short* h = (unsigned short*)(ws + off);
    unsigned short* agg = h + (size_t)N * D;

    int numTiles = (N + 31) / 32;
    int gemmGrid = numTiles < 768 ? numTiles : 768;
    int BPG = 1024;  // blocks per column-group; grid = 16 * BPG

    swizzle_w<<<512, 256, 0, stream>>>(W1, Wr, W1sw, Wrsw);
    build_row_ptr<<<(N + 256) / 256, 256, 0, stream>>>(erows, rp, N, E);
    gemm1_b<<<gemmGrid, 512, 0, stream>>>(right, W1sw, h, N, numTiles);
    scatter3<<<16 * BPG, 256, 0, stream>>>((const unsigned int*)h, rp, ecols, evals,
                                           (unsigned int*)agg, N, E, BPG);
    gemm2_b<<<gemmGrid, 512, 0, stream>>>(right, perm, Wrsw, br, agg, out, N, numTiles);
}

// Round 3
// 413.860 us; speedup vs baseline: 1.5306x; 1.5306x over previous
//
#include <hip/hip_runtime.h>
#include <hip/hip_bf16.h>
#include <math.h>

#define D 256

typedef short s16x8 __attribute__((ext_vector_type(8)));
typedef float f32x4 __attribute__((ext_vector_type(4)));

__device__ __forceinline__ unsigned short f2bf(float f) {
    unsigned int u = __builtin_bit_cast(unsigned int, f);
    unsigned int r = (u + 0x7fffu + ((u >> 16) & 1u)) >> 16;  // RNE
    return (unsigned short)r;
}
__device__ __forceinline__ float bf2f(unsigned short s) {
    unsigned int u = ((unsigned int)s) << 16;
    return __builtin_bit_cast(float, u);
}

__device__ __forceinline__ void gl_lds16(const unsigned short* g, unsigned short* l) {
    __builtin_amdgcn_global_load_lds(
        (const __attribute__((address_space(1))) unsigned int*)g,
        (__attribute__((address_space(3))) unsigned int*)l, 16, 0, 0);
}

// Wsw[((kt*16 + nt)*64 + lane)*8 + j] = bf16(W[kt*32 + (lane>>4)*8 + j][nt*16 + (lane&15)])
__global__ void swizzle_w(const float* __restrict__ W1, const float* __restrict__ Wr,
                          unsigned short* __restrict__ W1sw, unsigned short* __restrict__ Wrsw) {
    int idx = blockIdx.x * blockDim.x + threadIdx.x;  // 0 .. 2*65536-1
    int m = idx >> 16;
    int t = idx & 65535;
    const float* src = m ? Wr : W1;
    unsigned short* dst = m ? Wrsw : W1sw;
    int j = t & 7, lane = (t >> 3) & 63, nt = (t >> 9) & 15, kt = t >> 13;
    int k = kt * 32 + (lane >> 4) * 8 + j;
    int n = nt * 16 + (lane & 15);
    dst[t] = f2bf(src[k * D + n]);
}

__global__ void build_row_ptr(const int* __restrict__ rows, int* __restrict__ rp, int N, int E) {
    int r = blockIdx.x * blockDim.x + threadIdx.x;
    if (r > N) return;
    int lo = 0, hi = E;
    while (lo < hi) {
        int mid = (lo + hi) >> 1;
        if (rows[mid] < r) lo = mid + 1; else hi = mid;
    }
    rp[r] = lo;
}

// A-fragment packing: Xp[tile][fgi][j] (bf16) with fgi = (mt*8+kt)*64 + qd*16 + rl
// element = X[tile*32 + mt*16 + rl][kt*32 + qd*8 + j]  — exactly the GEMM LDS layout.
__device__ __forceinline__ void stage_a_frag(const float* __restrict__ Xrow, int k0,
                                             unsigned short* __restrict__ dst, int fgi) {
    float4 f0 = *(const float4*)(Xrow + k0);
    float4 f1 = *(const float4*)(Xrow + k0 + 4);
    s16x8 sf;
    sf[0] = (short)f2bf(f0.x); sf[1] = (short)f2bf(f0.y);
    sf[2] = (short)f2bf(f0.z); sf[3] = (short)f2bf(f0.w);
    sf[4] = (short)f2bf(f1.x); sf[5] = (short)f2bf(f1.y);
    sf[6] = (short)f2bf(f1.z); sf[7] = (short)f2bf(f1.w);
    *(s16x8*)(dst + (size_t)fgi * 8) = sf;
}

__global__ __launch_bounds__(256) void pack_x(const float* __restrict__ X,
                                              const int* __restrict__ perm,  // null => identity
                                              unsigned short* __restrict__ Xp,
                                              int N, int numTiles) {
    int idx = blockIdx.x * 256 + threadIdx.x;
    int total = numTiles << 10;
    if (idx >= total) return;
    int fgi = idx & 1023, tile = idx >> 10;
    int mt = fgi >> 9, kt = (fgi >> 6) & 7, ll = fgi & 63;
    int rl = ll & 15, qd = ll >> 4;
    int grow = tile * 32 + mt * 16 + rl;
    if (grow >= N) grow = N - 1;
    int row = perm ? perm[grow] : grow;
    stage_a_frag(X + (size_t)row * D, kt * 32 + qd * 8, Xp, idx);
}

// ---------------- GEMM: B persistent in registers, A via global_load_lds double-buffer --
// Block = 512 thr = 8 waves. Wave w owns cols [w*32, w*32+32).
__global__ __launch_bounds__(512) void gemm1_p(const unsigned short* __restrict__ Xp,
                                               const unsigned short* __restrict__ Wsw,
                                               unsigned short* __restrict__ h,
                                               int N, int numTiles) {
    __shared__ __attribute__((aligned(16))) unsigned short lA[2][8192];  // 2 x 16 KB
    int t = threadIdx.x;
    int lane = t & 63;
    int wave = t >> 6;
    int quad = lane >> 4;
    if ((int)blockIdx.x >= numTiles) return;

    s16x8 bfr[2][8];
#pragma unroll
    for (int ntl = 0; ntl < 2; ntl++) {
        int nt = wave * 2 + ntl;
#pragma unroll
        for (int kt = 0; kt < 8; kt++)
            bfr[ntl][kt] = *(const s16x8*)(Wsw + ((size_t)((kt * 16 + nt) * 64 + lane)) * 8);
    }

    int stride = gridDim.x;
    int ti = blockIdx.x;
    {
        const unsigned short* src = Xp + (size_t)ti * 8192;
        gl_lds16(src + wave * 512 + lane * 8, &lA[0][wave * 512]);
        gl_lds16(src + (wave + 8) * 512 + lane * 8, &lA[0][(wave + 8) * 512]);
    }
    int cur = 0;
    for (; ti < numTiles; ti += stride) {
        int nxt = ti + stride;
        if (nxt < numTiles) {
            const unsigned short* src = Xp + (size_t)nxt * 8192;
            gl_lds16(src + wave * 512 + lane * 8, &lA[cur ^ 1][wave * 512]);
            gl_lds16(src + (wave + 8) * 512 + lane * 8, &lA[cur ^ 1][(wave + 8) * 512]);
            asm volatile("s_waitcnt vmcnt(2)" ::: "memory");
        } else {
            asm volatile("s_waitcnt vmcnt(0)" ::: "memory");
        }
        __builtin_amdgcn_s_barrier();
        __builtin_amdgcn_sched_barrier(0);

        f32x4 acc[2][2];
#pragma unroll
        for (int mt = 0; mt < 2; mt++)
#pragma unroll
            for (int ntl = 0; ntl < 2; ntl++) acc[mt][ntl] = (f32x4){0.f, 0.f, 0.f, 0.f};

#pragma unroll
        for (int mt = 0; mt < 2; mt++)
#pragma unroll
            for (int kt = 0; kt < 8; kt++) {
                s16x8 a = *(const s16x8*)(&lA[cur][(size_t)(((mt * 8 + kt) * 64 + lane)) * 8]);
                acc[mt][0] = __builtin_amdgcn_mfma_f32_16x16x32_bf16(a, bfr[0][kt], acc[mt][0], 0, 0, 0);
                acc[mt][1] = __builtin_amdgcn_mfma_f32_16x16x32_bf16(a, bfr[1][kt], acc[mt][1], 0, 0, 0);
            }

#pragma unroll
        for (int mt = 0; mt < 2; mt++)
#pragma unroll
            for (int ntl = 0; ntl < 2; ntl++) {
                int col = (wave * 2 + ntl) * 16 + (lane & 15);
#pragma unroll
                for (int r = 0; r < 4; r++) {
                    int grow = ti * 32 + mt * 16 + quad * 4 + r;
                    if (grow < N) h[(size_t)grow * D + col] = f2bf(acc[mt][ntl][r]);
                }
            }
        __builtin_amdgcn_s_barrier();
        cur ^= 1;
    }
}

__global__ __launch_bounds__(512) void gemm2_p(const unsigned short* __restrict__ Xp,
                                               const unsigned short* __restrict__ Wsw,
                                               const float* __restrict__ br,
                                               const unsigned short* __restrict__ agg,
                                               float* __restrict__ out,
                                               int N, int numTiles) {
    __shared__ __attribute__((aligned(16))) unsigned short lA[2][8192];  // 2 x 16 KB
    int t = threadIdx.x;
    int lane = t & 63;
    int wave = t >> 6;
    int quad = lane >> 4;
    if ((int)blockIdx.x >= numTiles) return;

    s16x8 bfr[2][8];
#pragma unroll
    for (int ntl = 0; ntl < 2; ntl++) {
        int nt = wave * 2 + ntl;
#pragma unroll
        for (int kt = 0; kt < 8; kt++)
            bfr[ntl][kt] = *(const s16x8*)(Wsw + ((size_t)((kt * 16 + nt) * 64 + lane)) * 8);
    }

    int stride = gridDim.x;
    int ti = blockIdx.x;
    {
        const unsigned short* src = Xp + (size_t)ti * 8192;
        gl_lds16(src + wave * 512 + lane * 8, &lA[0][wave * 512]);
        gl_lds16(src + (wave + 8) * 512 + lane * 8, &lA[0][(wave + 8) * 512]);
    }
    int cur = 0;
    for (; ti < numTiles; ti += stride) {
        int nxt = ti + stride;
        if (nxt < numTiles) {
            const unsigned short* src = Xp + (size_t)nxt * 8192;
            gl_lds16(src + wave * 512 + lane * 8, &lA[cur ^ 1][wave * 512]);
            gl_lds16(src + (wave + 8) * 512 + lane * 8, &lA[cur ^ 1][(wave + 8) * 512]);
            asm volatile("s_waitcnt vmcnt(2)" ::: "memory");
        } else {
            asm volatile("s_waitcnt vmcnt(0)" ::: "memory");
        }
        __builtin_amdgcn_s_barrier();
        __builtin_amdgcn_sched_barrier(0);

        f32x4 acc[2][2];
#pragma unroll
        for (int mt = 0; mt < 2; mt++)
#pragma unroll
            for (int ntl = 0; ntl < 2; ntl++) acc[mt][ntl] = (f32x4){0.f, 0.f, 0.f, 0.f};

#pragma unroll
        for (int mt = 0; mt < 2; mt++)
#pragma unroll
            for (int kt = 0; kt < 8; kt++) {
                s16x8 a = *(const s16x8*)(&lA[cur][(size_t)(((mt * 8 + kt) * 64 + lane)) * 8]);
                acc[mt][0] = __builtin_amdgcn_mfma_f32_16x16x32_bf16(a, bfr[0][kt], acc[mt][0], 0, 0, 0);
                acc[mt][1] = __builtin_amdgcn_mfma_f32_16x16x32_bf16(a, bfr[1][kt], acc[mt][1], 0, 0, 0);
            }

        // epilogue: left = lA (bf16 of X[perm[row]], perm folded into pack) -> no gather
#pragma unroll
        for (int mt = 0; mt < 2; mt++) {
#pragma unroll
            for (int ntl = 0; ntl < 2; ntl++) {
                int col = (wave * 2 + ntl) * 16 + (lane & 15);
                float b = br[col];
                int kt2 = col >> 5, qd2 = (col >> 3) & 3, j2 = col & 7;
#pragma unroll
                for (int r = 0; r < 4; r++) {
                    int rt = mt * 16 + quad * 4 + r;
                    int grow = ti * 32 + rt;
                    if (grow < N) {
                        float pre = acc[mt][ntl][r] + b;
                        float gate = 1.f / (1.f + __expf(-pre));
                        float gcn = bf2f(agg[(size_t)grow * D + col]);
                        float left = bf2f(lA[cur][(size_t)(((mt * 8 + kt2) * 64 + qd2 * 16 + (rt & 15))) * 8 + j2]);
                        out[(size_t)grow * D + col] = gate * gcn + (1.f - gate) * left;
                    }
                }
            }
        }
        __builtin_amdgcn_s_barrier();
        cur ^= 1;
    }
}

// ---------------- Scatter: wave-per-row, readlane broadcast, 8-deep gather pipeline ----
__device__ __forceinline__ void acc4(float4& a, uint2 u, float v) {
    float x0 = __builtin_bit_cast(float, u.x << 16);
    float x1 = __builtin_bit_cast(float, u.x & 0xffff0000u);
    float x2 = __builtin_bit_cast(float, u.y << 16);
    float x3 = __builtin_bit_cast(float, u.y & 0xffff0000u);
    a.x += v * x0; a.y += v * x1; a.z += v * x2; a.w += v * x3;
}

__global__ __launch_bounds__(256) void scatter2(const uint2* __restrict__ hp,
                                                const int* __restrict__ rp,
                                                const int* __restrict__ cols,
                                                const float* __restrict__ vals,
                                                uint2* __restrict__ aggp,
                                                int N, int E) {
    int lane = threadIdx.x & 63;
    int wave = threadIdx.x >> 6;
    int row = blockIdx.x * 4 + wave;
    if (row >= N) return;
    int start = rp[row], end = rp[row + 1];

    float4 a = {0.f, 0.f, 0.f, 0.f};
    for (int base = start; base < end; base += 64) {
        int ii = base + lane;
        int iic = ii < E ? ii : E - 1;
        int cl = cols[iic];
        int vbits = __builtin_bit_cast(int, vals[iic]);
        int n = end - base; if (n > 64) n = 64;
        int i = 0;
        for (; i + 8 <= n; i += 8) {
            uint2 u[8]; float vv[8];
#pragma unroll
            for (int k = 0; k < 8; k++) {
                int c = __builtin_amdgcn_readlane(cl, i + k);
                vv[k] = __builtin_bit_cast(float, __builtin_amdgcn_readlane(vbits, i + k));
                u[k] = hp[(size_t)c * 64 + lane];
            }
#pragma unroll
            for (int k = 0; k < 8; k++) acc4(a, u[k], vv[k]);
        }
        for (; i < n; i++) {
            int c = __builtin_amdgcn_readlane(cl, i);
            float v = __builtin_bit_cast(float, __builtin_amdgcn_readlane(vbits, i));
            uint2 u = hp[(size_t)c * 64 + lane];
            acc4(a, u, v);
        }
    }
    a.x = fmaxf(a.x, 0.f); a.y = fmaxf(a.y, 0.f);
    a.z = fmaxf(a.z, 0.f); a.w = fmaxf(a.w, 0.f);
    uint2 o;
    o.x = (unsigned int)f2bf(a.x) | ((unsigned int)f2bf(a.y) << 16);
    o.y = (unsigned int)f2bf(a.z) | ((unsigned int)f2bf(a.w) << 16);
    aggp[(size_t)row * 64 + lane] = o;
}

extern "C" void kernel_launch(void* const* d_in, const int* in_sizes, int n_in,
                              void* d_out, int out_size, void* d_ws, size_t ws_size,
                              hipStream_t stream) {
    const float* right = (const float*)d_in[0];
    const float* W1    = (const float*)d_in[1];
    const float* Wr    = (const float*)d_in[2];
    const float* br    = (const float*)d_in[3];
    const float* evals = (const float*)d_in[4];
    const int*   erows = (const int*)d_in[5];
    const int*   ecols = (const int*)d_in[6];
    const int*   perm  = (const int*)d_in[7];
    int N = in_sizes[7];
    int E = in_sizes[4];
    float* out = (float*)d_out;

    int numTiles = (N + 31) / 32;
    size_t tileBytes = (size_t)numTiles * 16384;  // >= N*D*2

    char* ws = (char*)d_ws;
    unsigned short* W1sw = (unsigned short*)ws;
    unsigned short* Wrsw = W1sw + D * D;
    int* rp = (int*)(ws + (size_t)2 * D * D * 2);
    size_t off = (size_t)2 * D * D * 2 + 4 * (size_t)(N + 1);
    off = (off + 255) & ~(size_t)255;
    // region A (tileBytes): h, then reused as Xp2 (pack2 runs after scatter consumes h)
    unsigned short* h = (unsigned short*)(ws + off);
    unsigned short* Xp2 = h;
    // region B (tileBytes): Xp1 first (dead after gemm1), then agg (written by scatter)
    unsigned short* Xp1 = (unsigned short*)(ws + off + tileBytes);
    unsigned short* agg = Xp1;

    int packBlocks = (numTiles * 1024 + 255) / 256;
    int gemmGrid = numTiles < 512 ? numTiles : 512;

    swizzle_w<<<512, 256, 0, stream>>>(W1, Wr, W1sw, Wrsw);
    build_row_ptr<<<(N + 256) / 256, 256, 0, stream>>>(erows, rp, N, E);
    pack_x<<<packBlocks, 256, 0, stream>>>(right, (const int*)nullptr, Xp1, N, numTiles);
    gemm1_p<<<gemmGrid, 512, 0, stream>>>(Xp1, W1sw, h, N, numTiles);
    scatter2<<<(N + 3) / 4, 256, 0, stream>>>((const uint2*)h, rp, ecols, evals,
                                              (uint2*)agg, N, E);
    pack_x<<<packBlocks, 256, 0, stream>>>(right, perm, Xp2, N, numTiles);
    gemm2_p<<<gemmGrid, 512, 0, stream>>>(Xp2, W1sw == nullptr ? nullptr : Wrsw, br, agg, out, N, numTiles);
}

// Round 5
// 403.164 us; speedup vs baseline: 1.5712x; 1.0265x over previous
//
#include <hip/hip_runtime.h>
#include <hip/hip_bf16.h>
#include <math.h>

#define D 256

typedef short s16x8 __attribute__((ext_vector_type(8)));
typedef float f32x4 __attribute__((ext_vector_type(4)));

__device__ __forceinline__ unsigned short f2bf(float f) {
    unsigned int u = __builtin_bit_cast(unsigned int, f);
    unsigned int r = (u + 0x7fffu + ((u >> 16) & 1u)) >> 16;  // RNE
    return (unsigned short)r;
}
__device__ __forceinline__ float bf2f(unsigned short s) {
    unsigned int u = ((unsigned int)s) << 16;
    return __builtin_bit_cast(float, u);
}

// ---- pre: fused W-swizzle + row_ptr build ----
// Wsw[((kt*16 + nt)*64 + lane)*8 + j] = bf16(W[kt*32 + (lane>>4)*8 + j][nt*16 + (lane&15)])
__global__ void pre_k(const float* __restrict__ W1, const float* __restrict__ Wr,
                      unsigned short* __restrict__ W1sw, unsigned short* __restrict__ Wrsw,
                      const int* __restrict__ rows, int* __restrict__ rp, int N, int E) {
    int bid = blockIdx.x;
    if (bid < 512) {
        int idx = bid * 256 + threadIdx.x;  // 0 .. 131071
        int m = idx >> 16;
        int t = idx & 65535;
        const float* src = m ? Wr : W1;
        unsigned short* dst = m ? Wrsw : W1sw;
        int j = t & 7, lane = (t >> 3) & 63, nt = (t >> 9) & 15, kt = t >> 13;
        int k = kt * 32 + (lane >> 4) * 8 + j;
        int n = nt * 16 + (lane & 15);
        dst[t] = f2bf(src[k * D + n]);
    } else {
        int r = (bid - 512) * 256 + threadIdx.x;
        if (r > N) return;
        int lo = 0, hi = E;
        while (lo < hi) {
            int mid = (lo + hi) >> 1;
            if (rows[mid] < r) lo = mid + 1; else hi = mid;
        }
        rp[r] = lo;
    }
}

// ---------------- GEMM1: B persistent in registers, A staged in LDS (inline fp32->bf16) --
// Block = 512 thr = 8 waves. Wave w owns cols [w*32, w*32+32).
// LDS A layout = frag order: lA[((mt*8+kt)*64 + lane)*8 + j], mt in {0,1};
// element (row_in_tile rt, k): mt=rt>>4, rl=rt&15, kt=k>>5, qd=(k>>3)&3, j=k&7
//   -> lA[((mt*8+kt)*64 + qd*16 + rl)*8 + j]
__device__ __forceinline__ void stage_a_frag(const float* __restrict__ Xrow, int k0,
                                             unsigned short* __restrict__ lA, int fgi) {
    float4 f0 = *(const float4*)(Xrow + k0);
    float4 f1 = *(const float4*)(Xrow + k0 + 4);
    s16x8 sf;
    sf[0] = (short)f2bf(f0.x); sf[1] = (short)f2bf(f0.y);
    sf[2] = (short)f2bf(f0.z); sf[3] = (short)f2bf(f0.w);
    sf[4] = (short)f2bf(f1.x); sf[5] = (short)f2bf(f1.y);
    sf[6] = (short)f2bf(f1.z); sf[7] = (short)f2bf(f1.w);
    *(s16x8*)(lA + (size_t)fgi * 8) = sf;
}

__global__ __launch_bounds__(512) void gemm1_b(const float* __restrict__ X,
                                               const unsigned short* __restrict__ Wsw,
                                               unsigned short* __restrict__ h,
                                               int N, int numTiles) {
    __shared__ unsigned short lA[2 * 8 * 64 * 8];  // 16 KB
    int t = threadIdx.x;
    int lane = t & 63;
    int wave = t >> 6;
    int quad = lane >> 4;

    s16x8 bfr[2][8];
#pragma unroll
    for (int ntl = 0; ntl < 2; ntl++) {
        int nt = wave * 2 + ntl;
#pragma unroll
        for (int kt = 0; kt < 8; kt++)
            bfr[ntl][kt] = *(const s16x8*)(Wsw + ((size_t)((kt * 16 + nt) * 64 + lane)) * 8);
    }

    for (int tile = blockIdx.x; tile < numTiles; tile += gridDim.x) {
#pragma unroll
        for (int q = 0; q < 2; q++) {
            int fgi = q * 512 + t;
            int mt = fgi >> 9, kt = (fgi >> 6) & 7, ll = fgi & 63;
            int rl = ll & 15, qd = ll >> 4;
            int grow = tile * 32 + mt * 16 + rl;
            if (grow >= N) grow = N - 1;
            stage_a_frag(X + (size_t)grow * D, kt * 32 + qd * 8, lA, fgi);
        }
        __syncthreads();

        f32x4 acc[2][2];
#pragma unroll
        for (int mt = 0; mt < 2; mt++)
#pragma unroll
            for (int ntl = 0; ntl < 2; ntl++) acc[mt][ntl] = (f32x4){0.f, 0.f, 0.f, 0.f};

#pragma unroll
        for (int mt = 0; mt < 2; mt++)
#pragma unroll
            for (int kt = 0; kt < 8; kt++) {
                s16x8 a = *(const s16x8*)(lA + (size_t)(((mt * 8 + kt) * 64 + lane)) * 8);
                acc[mt][0] = __builtin_amdgcn_mfma_f32_16x16x32_bf16(a, bfr[0][kt], acc[mt][0], 0, 0, 0);
                acc[mt][1] = __builtin_amdgcn_mfma_f32_16x16x32_bf16(a, bfr[1][kt], acc[mt][1], 0, 0, 0);
            }

#pragma unroll
        for (int mt = 0; mt < 2; mt++)
#pragma unroll
            for (int ntl = 0; ntl < 2; ntl++) {
                int col = (wave * 2 + ntl) * 16 + (lane & 15);
#pragma unroll
                for (int r = 0; r < 4; r++) {
                    int grow = tile * 32 + mt * 16 + quad * 4 + r;
                    if (grow < N) h[(size_t)grow * D + col] = f2bf(acc[mt][ntl][r]);
                }
            }
        __syncthreads();
    }
}

// ---------------- GEMM2 fused with scatter: gate-GEMM + per-row gather + blend ----------
__device__ __forceinline__ void acc4(float4& a, uint2 u, float v) {
    float x0 = __builtin_bit_cast(float, u.x << 16);
    float x1 = __builtin_bit_cast(float, u.x & 0xffff0000u);
    float x2 = __builtin_bit_cast(float, u.y << 16);
    float x3 = __builtin_bit_cast(float, u.y & 0xffff0000u);
    a.x += v * x0; a.y += v * x1; a.z += v * x2; a.w += v * x3;
}

__global__ __launch_bounds__(512, 4) void gemm2_f(const float* __restrict__ X,
                                                  const int* __restrict__ perm,
                                                  const unsigned short* __restrict__ Wsw,
                                                  const float* __restrict__ br,
                                                  const uint2* __restrict__ hp,
                                                  const int* __restrict__ rp,
                                                  const int* __restrict__ cols,
                                                  const float* __restrict__ vals,
                                                  float* __restrict__ out,
                                                  int N, int E, int numTiles) {
    __shared__ unsigned short lA[2 * 8 * 64 * 8];        // 16 KB, A frags (left, bf16)
    __shared__ __attribute__((aligned(16))) float lAgg[32][260];  // 33.3 KB, fp32 agg tile
    int t = threadIdx.x;
    int lane = t & 63;
    int wave = t >> 6;
    int quad = lane >> 4;
    int tile = blockIdx.x;
    if (tile >= numTiles) return;

    // ---- stage A = bf16(X[perm[rows]]) ----
#pragma unroll
    for (int q = 0; q < 2; q++) {
        int fgi = q * 512 + t;
        int mt = fgi >> 9, kt = (fgi >> 6) & 7, ll = fgi & 63;
        int rl = ll & 15, qd = ll >> 4;
        int grow = tile * 32 + mt * 16 + rl;
        if (grow >= N) grow = N - 1;
        int pr = perm[grow];
        stage_a_frag(X + (size_t)pr * D, kt * 32 + qd * 8, lA, fgi);
    }

    // ---- B frags (Wr swizzled) ----
    s16x8 bfr[2][8];
#pragma unroll
    for (int ntl = 0; ntl < 2; ntl++) {
        int nt = wave * 2 + ntl;
#pragma unroll
        for (int kt = 0; kt < 8; kt++)
            bfr[ntl][kt] = *(const s16x8*)(Wsw + ((size_t)((kt * 16 + nt) * 64 + lane)) * 8);
    }
    __syncthreads();

    // ---- MFMA: gate pre-activation ----
    f32x4 acc[2][2];
#pragma unroll
    for (int mt = 0; mt < 2; mt++)
#pragma unroll
        for (int ntl = 0; ntl < 2; ntl++) acc[mt][ntl] = (f32x4){0.f, 0.f, 0.f, 0.f};

#pragma unroll
    for (int mt = 0; mt < 2; mt++)
#pragma unroll
        for (int kt = 0; kt < 8; kt++) {
            s16x8 a = *(const s16x8*)(lA + (size_t)(((mt * 8 + kt) * 64 + lane)) * 8);
            acc[mt][0] = __builtin_amdgcn_mfma_f32_16x16x32_bf16(a, bfr[0][kt], acc[mt][0], 0, 0, 0);
            acc[mt][1] = __builtin_amdgcn_mfma_f32_16x16x32_bf16(a, bfr[1][kt], acc[mt][1], 0, 0, 0);
        }

    // ---- fused scatter: wave w gathers rows tile*32 + w*4 .. +3 from h ----
#pragma unroll 1
    for (int rr = 0; rr < 4; rr++) {
        int row = tile * 32 + wave * 4 + rr;
        if (row >= N) break;
        int start = rp[row], end = rp[row + 1];
        float4 a = {0.f, 0.f, 0.f, 0.f};
        for (int base = start; base < end; base += 64) {
            int ii = base + lane;
            int iic = ii < E ? ii : E - 1;
            int cl = cols[iic];
            int vbits = __builtin_bit_cast(int, vals[iic]);
            int n = end - base; if (n > 64) n = 64;
            int i = 0;
            for (; i + 8 <= n; i += 8) {
                uint2 u[8]; float vv[8];
#pragma unroll
                for (int k = 0; k < 8; k++) {
                    int c = __builtin_amdgcn_readlane(cl, i + k);
                    vv[k] = __builtin_bit_cast(float, __builtin_amdgcn_readlane(vbits, i + k));
                    u[k] = hp[(size_t)c * 64 + lane];
                }
#pragma unroll
                for (int k = 0; k < 8; k++) acc4(a, u[k], vv[k]);
            }
            for (; i < n; i++) {
                int c = __builtin_amdgcn_readlane(cl, i);
                float v = __builtin_bit_cast(float, __builtin_amdgcn_readlane(vbits, i));
                uint2 u = hp[(size_t)c * 64 + lane];
                acc4(a, u, v);
            }
        }
        // relu, stash fp32 agg in LDS: lane covers cols lane*4 .. +3
        a.x = fmaxf(a.x, 0.f); a.y = fmaxf(a.y, 0.f);
        a.z = fmaxf(a.z, 0.f); a.w = fmaxf(a.w, 0.f);
        *(float4*)(&lAgg[wave * 4 + rr][lane * 4]) = a;
    }
    __syncthreads();

    // ---- epilogue: gate = sigmoid(acc + br); out = gate*gcn + (1-gate)*left ----
#pragma unroll
    for (int mt = 0; mt < 2; mt++) {
#pragma unroll
        for (int ntl = 0; ntl < 2; ntl++) {
            int col = (wave * 2 + ntl) * 16 + (lane & 15);
            float b = br[col];
            int kt2 = col >> 5, qd2 = (col >> 3) & 3, j2 = col & 7;
#pragma unroll
            for (int r = 0; r < 4; r++) {
                int rt = mt * 16 + quad * 4 + r;
                int grow = tile * 32 + rt;
                if (grow < N) {
                    float pre = acc[mt][ntl][r] + b;
                    float gate = 1.f / (1.f + __expf(-pre));
                    float gcn = lAgg[rt][col];
                    float left = bf2f(lA[(size_t)(((mt * 8 + kt2) * 64 + qd2 * 16 + (rt & 15))) * 8 + j2]);
                    out[(size_t)grow * D + col] = gate * gcn + (1.f - gate) * left;
                }
            }
        }
    }
}

extern "C" void kernel_launch(void* const* d_in, const int* in_sizes, int n_in,
                              void* d_out, int out_size, void* d_ws, size_t ws_size,
                              hipStream_t stream) {
    const float* right = (const float*)d_in[0];
    const float* W1    = (const float*)d_in[1];
    const float* Wr    = (const float*)d_in[2];
    const float* br    = (const float*)d_in[3];
    const float* evals = (const float*)d_in[4];
    const int*   erows = (const int*)d_in[5];
    const int*   ecols = (const int*)d_in[6];
    const int*   perm  = (const int*)d_in[7];
    int N = in_sizes[7];
    int E = in_sizes[4];
    float* out = (float*)d_out;

    char* ws = (char*)d_ws;
    unsigned short* W1sw = (unsigned short*)ws;
    unsigned short* Wrsw = W1sw + D * D;
    int* rp = (int*)(ws + (size_t)2 * D * D * 2);
    size_t off = (size_t)2 * D * D * 2 + 4 * (size_t)(N + 1);
    off = (off + 255) & ~(size_t)255;
    unsigned short* h = (unsigned short*)(ws + off);

    int numTiles = (N + 31) / 32;
    int rpBlocks = (N + 256) / 256;

    pre_k<<<512 + rpBlocks, 256, 0, stream>>>(W1, Wr, W1sw, Wrsw, erows, rp, N, E);
    gemm1_b<<<numTiles, 512, 0, stream>>>(right, W1sw, h, N, numTiles);
    gemm2_f<<<numTiles, 512, 0, stream>>>(right, perm, Wrsw, br, (const uint2*)h,
                                          rp, ecols, evals, out, N, E, numTiles);
}

// Round 8
// 395.052 us; speedup vs baseline: 1.6035x; 1.0205x over previous
//
#include <hip/hip_runtime.h>
#include <hip/hip_bf16.h>
#include <math.h>

#define D 256

typedef short s16x8 __attribute__((ext_vector_type(8)));
typedef float f32x4 __attribute__((ext_vector_type(4)));

__device__ __forceinline__ unsigned short f2bf(float f) {
    unsigned int u = __builtin_bit_cast(unsigned int, f);
    unsigned int r = (u + 0x7fffu + ((u >> 16) & 1u)) >> 16;  // RNE
    return (unsigned short)r;
}
__device__ __forceinline__ float bf2f(unsigned short s) {
    unsigned int u = ((unsigned int)s) << 16;
    return __builtin_bit_cast(float, u);
}

// ---- pre: W-swizzle + row_ptr build + X -> bf16 convert, one kernel ----
// Wsw[((kt*16 + nt)*64 + lane)*8 + j] = bf16(W[kt*32 + (lane>>4)*8 + j][nt*16 + (lane&15)])
__global__ void pre_all(const float* __restrict__ X,
                        const float* __restrict__ W1, const float* __restrict__ Wr,
                        unsigned short* __restrict__ Xbf,
                        unsigned short* __restrict__ W1sw, unsigned short* __restrict__ Wrsw,
                        const int* __restrict__ rows, int* __restrict__ rp,
                        int N, int E, int rpBlocks) {
    int bid = blockIdx.x;
    if (bid < 512) {
        int idx = bid * 256 + threadIdx.x;  // 0 .. 131071
        int m = idx >> 16;
        int t = idx & 65535;
        const float* src = m ? Wr : W1;
        unsigned short* dst = m ? Wrsw : W1sw;
        int j = t & 7, lane = (t >> 3) & 63, nt = (t >> 9) & 15, kt = t >> 13;
        int k = kt * 32 + (lane >> 4) * 8 + j;
        int n = nt * 16 + (lane & 15);
        dst[t] = f2bf(src[k * D + n]);
    } else if (bid < 512 + rpBlocks) {
        int r = (bid - 512) * 256 + threadIdx.x;
        if (r > N) return;
        int lo = 0, hi = E;
        while (lo < hi) {
            int mid = (lo + hi) >> 1;
            if (rows[mid] < r) lo = mid + 1; else hi = mid;
        }
        rp[r] = lo;
    } else {
        long long c = (long long)(bid - 512 - rpBlocks) * 256 + threadIdx.x;
        long long i8 = c * 8;
        if (i8 >= (long long)N * D) return;
        float4 f0 = *(const float4*)(X + i8);
        float4 f1 = *(const float4*)(X + i8 + 4);
        s16x8 sf;
        sf[0] = (short)f2bf(f0.x); sf[1] = (short)f2bf(f0.y);
        sf[2] = (short)f2bf(f0.z); sf[3] = (short)f2bf(f0.w);
        sf[4] = (short)f2bf(f1.x); sf[5] = (short)f2bf(f1.y);
        sf[6] = (short)f2bf(f1.z); sf[7] = (short)f2bf(f1.w);
        *(s16x8*)(Xbf + i8) = sf;
    }
}

// ---------------- Scatter on Xbf: aggX = A * Xbf (no relu) ----------------
// Verbatim round-0/1 scatter2 structure (proven 116 us @ 73% occ), source = Xbf.
__device__ __forceinline__ void acc4(float4& a, uint2 u, float v) {
    float x0 = __builtin_bit_cast(float, u.x << 16);
    float x1 = __builtin_bit_cast(float, u.x & 0xffff0000u);
    float x2 = __builtin_bit_cast(float, u.y << 16);
    float x3 = __builtin_bit_cast(float, u.y & 0xffff0000u);
    a.x += v * x0; a.y += v * x1; a.z += v * x2; a.w += v * x3;
}

__global__ __launch_bounds__(256) void scatter_x(const uint2* __restrict__ xp,
                                                 const int* __restrict__ rp,
                                                 const int* __restrict__ cols,
                                                 const float* __restrict__ vals,
                                                 uint2* __restrict__ aggp,
                                                 int N, int E) {
    int lane = threadIdx.x & 63;
    int wave = threadIdx.x >> 6;
    int row = blockIdx.x * 4 + wave;
    if (row >= N) return;
    int start = rp[row], end = rp[row + 1];

    float4 a = {0.f, 0.f, 0.f, 0.f};
    for (int base = start; base < end; base += 64) {
        int ii = base + lane;
        int iic = ii < E ? ii : E - 1;
        int cl = cols[iic];
        int vbits = __builtin_bit_cast(int, vals[iic]);
        int n = end - base; if (n > 64) n = 64;
        int i = 0;
        for (; i + 8 <= n; i += 8) {
            uint2 u[8]; float vv[8];
#pragma unroll
            for (int k = 0; k < 8; k++) {
                int c = __builtin_amdgcn_readlane(cl, i + k);
                vv[k] = __builtin_bit_cast(float, __builtin_amdgcn_readlane(vbits, i + k));
                u[k] = xp[(size_t)c * 64 + lane];
            }
#pragma unroll
            for (int k = 0; k < 8; k++) acc4(a, u[k], vv[k]);
        }
        for (; i < n; i++) {
            int c = __builtin_amdgcn_readlane(cl, i);
            float v = __builtin_bit_cast(float, __builtin_amdgcn_readlane(vbits, i));
            uint2 u = xp[(size_t)c * 64 + lane];
            acc4(a, u, v);
        }
    }
    // NO relu here: relu is applied after @W1 (relu((A X) W1) == relu(A (X W1)))
    uint2 o;
    o.x = (unsigned int)f2bf(a.x) | ((unsigned int)f2bf(a.y) << 16);
    o.y = (unsigned int)f2bf(a.z) | ((unsigned int)f2bf(a.w) << 16);
    aggp[(size_t)row * 64 + lane] = o;
}

// ---------------- gemm_ff: gcn = relu(aggX @ W1), gate = sigmoid(Xbf[perm] @ Wr + br),
//                  out = gate*gcn + (1-gate)*left.  Both A operands already bf16. ----
// Block = 512 thr = 8 waves, one 32-row tile. Wave w owns cols [w*32, w*32+32).
// A-fragment (mt,kt) at lane l = element (row tile*32+mt*16+(l&15), k = kt*32+(l>>4)*8 + j)
//   -> direct 16B load from a row-major bf16 matrix. No conversion, no LDS for aggX.
__global__ __launch_bounds__(512, 4) void gemm_ff(const unsigned short* __restrict__ aggX,
                                                  const unsigned short* __restrict__ Xbf,
                                                  const int* __restrict__ perm,
                                                  const unsigned short* __restrict__ W1sw,
                                                  const unsigned short* __restrict__ Wrsw,
                                                  const float* __restrict__ br,
                                                  float* __restrict__ out,
                                                  int N, int numTiles) {
    __shared__ unsigned short lA[8 * 64 * 16];  // 16 KB: left frags (bf16 Xbf[perm])
    int t = threadIdx.x;
    int lane = t & 63;
    int wave = t >> 6;
    int quad = lane >> 4;
    int tile = blockIdx.x;
    if (tile >= numTiles) return;

    // stage left = Xbf[perm[rows]] into LDS frag layout (straight bf16 copy)
#pragma unroll
    for (int q = 0; q < 2; q++) {
        int fgi = q * 512 + t;
        int mt = fgi >> 9, kt = (fgi >> 6) & 7, ll = fgi & 63;
        int rl = ll & 15, qd = ll >> 4;
        int grow = tile * 32 + mt * 16 + rl;
        if (grow >= N) grow = N - 1;
        int pr = perm[grow];
        *(s16x8*)(lA + (size_t)fgi * 8) = *(const s16x8*)(Xbf + (size_t)pr * D + kt * 32 + qd * 8);
    }

    // ---- phase 1: acc1 = aggX @ W1 (A direct from global) ----
    s16x8 bfr[2][8];
#pragma unroll
    for (int ntl = 0; ntl < 2; ntl++) {
        int nt = wave * 2 + ntl;
#pragma unroll
        for (int kt = 0; kt < 8; kt++)
            bfr[ntl][kt] = *(const s16x8*)(W1sw + ((size_t)((kt * 16 + nt) * 64 + lane)) * 8);
    }
    f32x4 acc1[2][2];
#pragma unroll
    for (int mt = 0; mt < 2; mt++)
#pragma unroll
        for (int ntl = 0; ntl < 2; ntl++) acc1[mt][ntl] = (f32x4){0.f, 0.f, 0.f, 0.f};

#pragma unroll
    for (int mt = 0; mt < 2; mt++) {
        int grow = tile * 32 + mt * 16 + (lane & 15);
        if (grow >= N) grow = N - 1;
        const unsigned short* ap = aggX + (size_t)grow * D + (lane >> 4) * 8;
#pragma unroll
        for (int kt = 0; kt < 8; kt++) {
            s16x8 a = *(const s16x8*)(ap + kt * 32);
            acc1[mt][0] = __builtin_amdgcn_mfma_f32_16x16x32_bf16(a, bfr[0][kt], acc1[mt][0], 0, 0, 0);
            acc1[mt][1] = __builtin_amdgcn_mfma_f32_16x16x32_bf16(a, bfr[1][kt], acc1[mt][1], 0, 0, 0);
        }
    }
    __syncthreads();  // lA staging visible for phase 2 + epilogue

    // ---- phase 2: acc2 = Xbf[perm] @ Wr (A from LDS) ----
#pragma unroll
    for (int ntl = 0; ntl < 2; ntl++) {
        int nt = wave * 2 + ntl;
#pragma unroll
        for (int kt = 0; kt < 8; kt++)
            bfr[ntl][kt] = *(const s16x8*)(Wrsw + ((size_t)((kt * 16 + nt) * 64 + lane)) * 8);
    }
    f32x4 acc2[2][2];
#pragma unroll
    for (int mt = 0; mt < 2; mt++)
#pragma unroll
        for (int ntl = 0; ntl < 2; ntl++) acc2[mt][ntl] = (f32x4){0.f, 0.f, 0.f, 0.f};

#pragma unroll
    for (int mt = 0; mt < 2; mt++)
#pragma unroll
        for (int kt = 0; kt < 8; kt++) {
            s16x8 a = *(const s16x8*)(lA + (size_t)(((mt * 8 + kt) * 64 + lane)) * 8);
            acc2[mt][0] = __builtin_amdgcn_mfma_f32_16x16x32_bf16(a, bfr[0][kt], acc2[mt][0], 0, 0, 0);
            acc2[mt][1] = __builtin_amdgcn_mfma_f32_16x16x32_bf16(a, bfr[1][kt], acc2[mt][1], 0, 0, 0);
        }

    // ---- epilogue ----
#pragma unroll
    for (int mt = 0; mt < 2; mt++) {
#pragma unroll
        for (int ntl = 0; ntl < 2; ntl++) {
            int col = (wave * 2 + ntl) * 16 + (lane & 15);
            float b = br[col];
            int kt2 = col >> 5, qd2 = (col >> 3) & 3, j2 = col & 7;
#pragma unroll
            for (int r = 0; r < 4; r++) {
                int rt = mt * 16 + quad * 4 + r;
                int grow = tile * 32 + rt;
                if (grow < N) {
                    float pre = acc2[mt][ntl][r] + b;
                    float gate = 1.f / (1.f + __expf(-pre));
                    float gcn = fmaxf(acc1[mt][ntl][r], 0.f);
                    float left = bf2f(lA[(size_t)(((mt * 8 + kt2) * 64 + qd2 * 16 + (rt & 15))) * 8 + j2]);
                    out[(size_t)grow * D + col] = gate * gcn + (1.f - gate) * left;
                }
            }
        }
    }
}

extern "C" void kernel_launch(void* const* d_in, const int* in_sizes, int n_in,
                              void* d_out, int out_size, void* d_ws, size_t ws_size,
                              hipStream_t stream) {
    const float* right = (const float*)d_in[0];
    const float* W1    = (const float*)d_in[1];
    const float* Wr    = (const float*)d_in[2];
    const float* br    = (const float*)d_in[3];
    const float* evals = (const float*)d_in[4];
    const int*   erows = (const int*)d_in[5];
    const int*   ecols = (const int*)d_in[6];
    const int*   perm  = (const int*)d_in[7];
    int N = in_sizes[7];
    int E = in_sizes[4];
    float* out = (float*)d_out;

    char* ws = (char*)d_ws;
    unsigned short* W1sw = (unsigned short*)ws;
    unsigned short* Wrsw = W1sw + D * D;
    int* rp = (int*)(ws + (size_t)2 * D * D * 2);
    size_t off = (size_t)2 * D * D * 2 + 4 * (size_t)(N + 1);
    off = (off + 255) & ~(size_t)255;
    unsigned short* Xbf = (unsigned short*)(ws + off);
    unsigned short* aggX = Xbf + (size_t)N * D;

    int numTiles = (N + 31) / 32;
    int rpBlocks = (N + 256) / 256;
    long long cvtElems = (long long)N * D / 8;
    int cvtBlocks = (int)((cvtElems + 255) / 256);

    pre_all<<<512 + rpBlocks + cvtBlocks, 256, 0, stream>>>(right, W1, Wr, Xbf, W1sw, Wrsw,
                                                            erows, rp, N, E, rpBlocks);
    scatter_x<<<(N + 3) / 4, 256, 0, stream>>>((const uint2*)Xbf, rp, ecols, evals,
                                               (uint2*)aggX, N, E);
    gemm_ff<<<numTiles, 512, 0, stream>>>(aggX, Xbf, perm, W1sw, Wrsw, br, out, N, numTiles);
}